// Round 2
// baseline (156.426 us; speedup 1.0000x reference)
//
#include <hip/hip_runtime.h>

// LFR frame stacking: x (B=64, T=4096, D=80) f32, lens (B,) i32
// out (B, NF=683, M*D=560) f32 ++ new_len (B,) f32
//
// Semantics (verified R1, absmax=0): T_all_max = 4099 fixed (lens[0]=T),
// NF = 683. For output position t = 6f+m:
//   src = 0 if t<3; t-3 if t<3+lens[b]; else T-1 = 4095
// (reference's where() clamp lands inside x, the tail repeat is never read).
//
// R2: grid-stride 4 float4/thread (amortize idx math), nontemporal stores
// for out (keep L2 for the 7/6-overlap x reuse).

constexpr int B    = 64;
constexpr int T    = 4096;
constexpr int D    = 80;
constexpr int NF   = 683;
constexpr int M    = 7;
constexpr int N    = 6;
constexpr int LEFT = 3;

constexpr int D4     = D / 4;         // 20 float4 per frame
constexpr int ROW4   = M * D4;        // 140 float4 per output row
constexpr int TOTAL4 = B * NF * ROW4; // 6,119,680 float4 total
constexpr int ITEMS  = 4;
constexpr int BLOCK  = 256;
constexpr int GRID   = (TOTAL4 + BLOCK * ITEMS - 1) / (BLOCK * ITEMS); // 5977

__global__ __launch_bounds__(BLOCK) void lfr_kernel(
    const float4* __restrict__ x,       // (B*T*D4)
    const int*    __restrict__ lens,    // (B,)
    float4*       __restrict__ out,     // (B*NF*ROW4)
    float*        __restrict__ new_len) // (B,)
{
    const int nthreads = GRID * BLOCK;
    int idx = blockIdx.x * BLOCK + threadIdx.x;

    // fused tiny output: new_len
    if (blockIdx.x == 0 && threadIdx.x < B) {
        int L   = lens[threadIdx.x];
        int rem = L % N;
        int rp  = (rem == 1) ? 3 : (rem == 2) ? 2 : (rem == 3) ? 1 : 0;
        new_len[threadIdx.x] = (float)((LEFT + L + rp) / N);
    }

    #pragma unroll
    for (int it = 0; it < ITEMS; ++it, idx += nthreads) {
        if (idx >= TOTAL4) break;

        int row = idx / ROW4;          // (b, f) flat
        int r   = idx - row * ROW4;    // [0,140)
        int b   = row / NF;
        int f   = row - b * NF;
        int m   = r / D4;              // frame within window
        int d4  = r - m * D4;          // float4 within frame

        int t = f * N + m;
        int L = lens[b];

        int src;
        if (t < LEFT)              src = 0;
        else if (t < LEFT + L)     src = t - LEFT;
        else                       src = T - 1;

        float4 v = x[(b * T + src) * D4 + d4];
        __builtin_nontemporal_store(v.x, &out[idx].x);
        __builtin_nontemporal_store(v.y, &out[idx].y);
        __builtin_nontemporal_store(v.z, &out[idx].z);
        __builtin_nontemporal_store(v.w, &out[idx].w);
    }
}

extern "C" void kernel_launch(void* const* d_in, const int* in_sizes, int n_in,
                              void* d_out, int out_size, void* d_ws, size_t ws_size,
                              hipStream_t stream) {
    const float4* x    = (const float4*)d_in[0];
    const int*    lens = (const int*)d_in[1];
    float*        out  = (float*)d_out;
    float*        nl   = out + (size_t)B * NF * M * D; // new_len after main output

    lfr_kernel<<<GRID, BLOCK, 0, stream>>>(x, lens, (float4*)out, nl);
}

// Round 3
// 155.317 us; speedup vs baseline: 1.0071x; 1.0071x over previous
//
#include <hip/hip_runtime.h>

// LFR frame stacking: x (B=64, T=4096, D=80) f32, lens (B,) i32
// out (B, NF=683, M*D=560) f32 ++ new_len (B,) f32
//
// Semantics (verified R1, absmax=0): T_all_max = 4099 fixed (lens[0]=T),
// NF = 683. For output position t = 6f+m:
//   src = 0 if t<3; t-3 if t<3+lens[b]; else T-1 = 4095
// (reference's where() clamp lands inside x; the tail repeat is never read).
//
// R3: plain stores (NT regressed −2% in R2); block-contiguous tiling
// (4 items per thread within one 16 KB block tile — same b, L1-warm reads).

constexpr int B    = 64;
constexpr int T    = 4096;
constexpr int D    = 80;
constexpr int NF   = 683;
constexpr int M    = 7;
constexpr int N    = 6;
constexpr int LEFT = 3;

constexpr int D4     = D / 4;         // 20 float4 per frame
constexpr int ROW4   = M * D4;        // 140 float4 per output row
constexpr int TOTAL4 = B * NF * ROW4; // 6,119,680 float4 total
constexpr int ITEMS  = 4;
constexpr int BLOCK  = 256;
constexpr int TILE   = BLOCK * ITEMS; // 1024 float4 per block
constexpr int GRID   = (TOTAL4 + TILE - 1) / TILE; // 5977

__global__ __launch_bounds__(BLOCK) void lfr_kernel(
    const float4* __restrict__ x,       // (B*T*D4)
    const int*    __restrict__ lens,    // (B,)
    float4*       __restrict__ out,     // (B*NF*ROW4)
    float*        __restrict__ new_len) // (B,)
{
    // fused tiny output: new_len
    if (blockIdx.x == 0 && threadIdx.x < B) {
        int L   = lens[threadIdx.x];
        int rem = L % N;
        int rp  = (rem == 1) ? 3 : (rem == 2) ? 2 : (rem == 3) ? 1 : 0;
        new_len[threadIdx.x] = (float)((LEFT + L + rp) / N);
    }

    int base = blockIdx.x * TILE + threadIdx.x;

    #pragma unroll
    for (int it = 0; it < ITEMS; ++it) {
        int idx = base + it * BLOCK;
        if (idx >= TOTAL4) break;

        int row = idx / ROW4;          // (b, f) flat
        int r   = idx - row * ROW4;    // [0,140)
        int b   = row / NF;
        int f   = row - b * NF;
        int m   = r / D4;              // frame within window
        int d4  = r - m * D4;          // float4 within frame

        int t = f * N + m;
        int L = lens[b];

        int src;
        if (t < LEFT)              src = 0;
        else if (t < LEFT + L)     src = t - LEFT;
        else                       src = T - 1;

        out[idx] = x[(b * T + src) * D4 + d4];
    }
}

extern "C" void kernel_launch(void* const* d_in, const int* in_sizes, int n_in,
                              void* d_out, int out_size, void* d_ws, size_t ws_size,
                              hipStream_t stream) {
    const float4* x    = (const float4*)d_in[0];
    const int*    lens = (const int*)d_in[1];
    float*        out  = (float*)d_out;
    float*        nl   = out + (size_t)B * NF * M * D; // new_len after main output

    lfr_kernel<<<GRID, BLOCK, 0, stream>>>(x, lens, (float4*)out, nl);
}